// Round 16
// baseline (99.049 us; speedup 1.0000x reference)
//
#include <hip/hip_runtime.h>

#define SQRT2f 1.41421356237309515f
#define SQRT3f 1.73205080756887729f

__device__ __forceinline__ float2 cmul(float2 a, float2 b) {
  return make_float2(a.x*b.x - a.y*b.y, a.x*b.y + a.y*b.x);
}
__device__ __forceinline__ float2 cadd(float2 a, float2 b) {
  return make_float2(a.x + b.x, a.y + b.y);
}

// ---- float4 = two complex amps (re0,im0,re1,im1), transformed identically ----
__device__ __forceinline__ float4 f4m(float a, float4 v) {
  return make_float4(a*v.x, a*v.y, a*v.z, a*v.w);
}
__device__ __forceinline__ float4 f4ma(float a, float4 v, float4 acc) {
  return make_float4(acc.x+a*v.x, acc.y+a*v.y, acc.z+a*v.z, acc.w+a*v.w);
}
__device__ __forceinline__ float4 f4ms(float a, float4 v, float4 acc) { // acc - a*v
  return make_float4(acc.x-a*v.x, acc.y-a*v.y, acc.z-a*v.z, acc.w-a*v.w);
}
__device__ __forceinline__ float4 cmul4(float2 C, float4 v) {
  return make_float4(C.x*v.x - C.y*v.y, C.x*v.y + C.y*v.x,
                     C.x*v.z - C.y*v.w, C.x*v.w + C.y*v.z);
}
__device__ __forceinline__ float4 cfma4(float2 C, float4 v, float4 acc) {
  return make_float4(acc.x + C.x*v.x - C.y*v.y, acc.y + C.x*v.y + C.y*v.x,
                     acc.z + C.x*v.z - C.y*v.w, acc.w + C.x*v.w + C.y*v.z);
}

// BS real rotation applied to float4 q's (q = 3*outer+inner), rows 0,8 identity
#define BS4C(v01,v02,v10,v11,v12,v20,v21, c,s,c2,s2,cc,ss,rcs) { \
  { float4 t1=v01, t3=v10; \
    v01 = f4ms(s,t3,f4m(c,t1)); v10 = f4ma(c,t3,f4m(s,t1)); } \
  { float4 t2=v02, t4=v11, t6=v20; \
    v02 = f4ma(ss,t6, f4ms(rcs,t4, f4m(cc,t2))); \
    v11 = f4ms(rcs,t6, f4ma(c2,t4, f4m(rcs,t2))); \
    v20 = f4ma(cc,t6, f4ma(rcs,t4, f4m(ss,t2))); } \
  { float4 t5=v12, t7=v21; \
    v12 = f4ms(s2,t7, f4m(c2,t5)); v21 = f4ma(c2,t7, f4m(s2,t5)); } }

// ---- wide plain BS (k<=3): strides in float4 units ----
template<int SO, int SI>
__device__ __forceinline__ void bs_w(float4* __restrict__ P, int b, float2 cs) {
  const float c=cs.x, s=cs.y;
  const float c2=c*c-s*s, s2=2.f*c*s, cc=c*c, ss=s*s, rcs=SQRT2f*c*s;
  float4 v01=P[b+SI],      v10=P[b+SO];
  float4 v02=P[b+2*SI],    v11=P[b+SO+SI],  v20=P[b+2*SO];
  float4 v12=P[b+SO+2*SI], v21=P[b+2*SO+SI];
  BS4C(v01,v02,v10,v11,v12,v20,v21, c,s,c2,s2,cc,ss,rcs);
  P[b+SI]=v01; P[b+SO]=v10; P[b+2*SI]=v02; P[b+SO+SI]=v11; P[b+2*SO]=v20;
  P[b+SO+2*SI]=v12; P[b+2*SO+SI]=v21;
}

// ---- wide fused (SQ_A outer ⊗ SQ_B inner) then BS ----
template<int SO, int SI>
__device__ __forceinline__ void sqbs_w(float4* __restrict__ P, int b,
                                       const float2* __restrict__ G, float2 cs) {
  float2 A00=G[0],A02=G[1],A11=G[2],A20=G[3],A22=G[4];
  float2 B00=G[5],B02=G[6],B11=G[7],B20=G[8],B22=G[9];
  float4 v00=P[b],      v01=P[b+SI],      v02=P[b+2*SI];
  float4 v10=P[b+SO],   v11=P[b+SO+SI],   v12=P[b+SO+2*SI];
  float4 v20=P[b+2*SO], v21=P[b+2*SO+SI], v22=P[b+2*SO+2*SI];
  { float4 u0=v00,u2=v02; v00=cfma4(B02,u2,cmul4(B00,u0)); v01=cmul4(B11,v01); v02=cfma4(B22,u2,cmul4(B20,u0)); }
  { float4 u0=v10,u2=v12; v10=cfma4(B02,u2,cmul4(B00,u0)); v11=cmul4(B11,v11); v12=cfma4(B22,u2,cmul4(B20,u0)); }
  { float4 u0=v20,u2=v22; v20=cfma4(B02,u2,cmul4(B00,u0)); v21=cmul4(B11,v21); v22=cfma4(B22,u2,cmul4(B20,u0)); }
  { float4 u0=v00,u2=v20; v00=cfma4(A02,u2,cmul4(A00,u0)); v10=cmul4(A11,v10); v20=cfma4(A22,u2,cmul4(A20,u0)); }
  { float4 u0=v01,u2=v21; v01=cfma4(A02,u2,cmul4(A00,u0)); v11=cmul4(A11,v11); v21=cfma4(A22,u2,cmul4(A20,u0)); }
  { float4 u0=v02,u2=v22; v02=cfma4(A02,u2,cmul4(A00,u0)); v12=cmul4(A11,v12); v22=cfma4(A22,u2,cmul4(A20,u0)); }
  const float c=cs.x, s=cs.y;
  const float c2=c*c-s*s, s2=2.f*c*s, cc=c*c, ss=s*s, rcs=SQRT2f*c*s;
  BS4C(v01,v02,v10,v11,v12,v20,v21, c,s,c2,s2,cc,ss,rcs);
  P[b]=v00; P[b+SI]=v01; P[b+2*SI]=v02;
  P[b+SO]=v10; P[b+SO+SI]=v11; P[b+SO+2*SI]=v12;
  P[b+2*SO]=v20; P[b+2*SO+SI]=v21; P[b+2*SO+2*SI]=v22;
}

// ---- wide fused (DPK_A outer ⊗ DPK_B inner, dense) then BS ----
template<int SO, int SI>
__device__ __forceinline__ void dpbs_w(float4* __restrict__ P, int b,
                                       const float2* __restrict__ G, float2 cs) {
  float4 v00=P[b],      v01=P[b+SI],      v02=P[b+2*SI];
  float4 v10=P[b+SO],   v11=P[b+SO+SI],   v12=P[b+SO+2*SI];
  float4 v20=P[b+2*SO], v21=P[b+2*SO+SI], v22=P[b+2*SO+2*SI];
  { float4 u0=v00,u1=v01,u2=v02;
    v00 = cfma4(G[11],u2, cfma4(G[10],u1, cmul4(G[9], u0)));
    v01 = cfma4(G[14],u2, cfma4(G[13],u1, cmul4(G[12],u0)));
    v02 = cfma4(G[17],u2, cfma4(G[16],u1, cmul4(G[15],u0))); }
  { float4 u0=v10,u1=v11,u2=v12;
    v10 = cfma4(G[11],u2, cfma4(G[10],u1, cmul4(G[9], u0)));
    v11 = cfma4(G[14],u2, cfma4(G[13],u1, cmul4(G[12],u0)));
    v12 = cfma4(G[17],u2, cfma4(G[16],u1, cmul4(G[15],u0))); }
  { float4 u0=v20,u1=v21,u2=v22;
    v20 = cfma4(G[11],u2, cfma4(G[10],u1, cmul4(G[9], u0)));
    v21 = cfma4(G[14],u2, cfma4(G[13],u1, cmul4(G[12],u0)));
    v22 = cfma4(G[17],u2, cfma4(G[16],u1, cmul4(G[15],u0))); }
  { float4 u0=v00,u1=v10,u2=v20;
    v00 = cfma4(G[2],u2, cfma4(G[1],u1, cmul4(G[0],u0)));
    v10 = cfma4(G[5],u2, cfma4(G[4],u1, cmul4(G[3],u0)));
    v20 = cfma4(G[8],u2, cfma4(G[7],u1, cmul4(G[6],u0))); }
  { float4 u0=v01,u1=v11,u2=v21;
    v01 = cfma4(G[2],u2, cfma4(G[1],u1, cmul4(G[0],u0)));
    v11 = cfma4(G[5],u2, cfma4(G[4],u1, cmul4(G[3],u0)));
    v21 = cfma4(G[8],u2, cfma4(G[7],u1, cmul4(G[6],u0))); }
  { float4 u0=v02,u1=v12,u2=v22;
    v02 = cfma4(G[2],u2, cfma4(G[1],u1, cmul4(G[0],u0)));
    v12 = cfma4(G[5],u2, cfma4(G[4],u1, cmul4(G[3],u0)));
    v22 = cfma4(G[8],u2, cfma4(G[7],u1, cmul4(G[6],u0))); }
  const float c=cs.x, s=cs.y;
  const float c2=c*c-s*s, s2=2.f*c*s, cc=c*c, ss=s*s, rcs=SQRT2f*c*s;
  BS4C(v01,v02,v10,v11,v12,v20,v21, c,s,c2,s2,cc,ss,rcs);
  P[b]=v00; P[b+SI]=v01; P[b+2*SI]=v02;
  P[b+SO]=v10; P[b+SO+SI]=v11; P[b+SO+2*SI]=v12;
  P[b+2*SO]=v20; P[b+2*SO+SI]=v21; P[b+2*SO+2*SI]=v22;
}

// ---- k=4 narrow (pair modes 4,5; float2, offsets {0,1,2,4,5,6,8,9,10}) ----
#define BS2C(v01,v02,v10,v11,v12,v20,v21, c,s,c2,s2,cc,ss,rcs) { \
  { float2 t1=v01, t3=v10; \
    v01 = make_float2(c*t1.x - s*t3.x, c*t1.y - s*t3.y); \
    v10 = make_float2(s*t1.x + c*t3.x, s*t1.y + c*t3.y); } \
  { float2 t2=v02, t4=v11, t6=v20; \
    v02 = make_float2(cc*t2.x - rcs*t4.x + ss*t6.x, cc*t2.y - rcs*t4.y + ss*t6.y); \
    v11 = make_float2(rcs*t2.x + c2*t4.x - rcs*t6.x, rcs*t2.y + c2*t4.y - rcs*t6.y); \
    v20 = make_float2(ss*t2.x + rcs*t4.x + cc*t6.x, ss*t2.y + rcs*t4.y + cc*t6.y); } \
  { float2 t5=v12, t7=v21; \
    v12 = make_float2(c2*t5.x - s2*t7.x, c2*t5.y - s2*t7.y); \
    v21 = make_float2(s2*t5.x + c2*t7.x, s2*t5.y + c2*t7.y); } }

__device__ __forceinline__ void bs_n4(float2* __restrict__ p2, int b, float2 cs) {
  const float c=cs.x, s=cs.y;
  const float c2=c*c-s*s, s2=2.f*c*s, cc=c*c, ss=s*s, rcs=SQRT2f*c*s;
  float2 v01=p2[b+1], v02=p2[b+2], v10=p2[b+4], v11=p2[b+5], v12=p2[b+6];
  float2 v20=p2[b+8], v21=p2[b+9];
  BS2C(v01,v02,v10,v11,v12,v20,v21, c,s,c2,s2,cc,ss,rcs);
  p2[b+1]=v01; p2[b+2]=v02; p2[b+4]=v10; p2[b+5]=v11; p2[b+6]=v12;
  p2[b+8]=v20; p2[b+9]=v21;
}

__device__ __forceinline__ void sqbs_n4(float2* __restrict__ p2, int b,
                                        const float2* __restrict__ G, float2 cs) {
  float2 A00=G[0],A02=G[1],A11=G[2],A20=G[3],A22=G[4];
  float2 B00=G[5],B02=G[6],B11=G[7],B20=G[8],B22=G[9];
  float2 v00=p2[b],   v01=p2[b+1], v02=p2[b+2];
  float2 v10=p2[b+4], v11=p2[b+5], v12=p2[b+6];
  float2 v20=p2[b+8], v21=p2[b+9], v22=p2[b+10];
  { float2 u0=v00,u2=v02; v00=cadd(cmul(B00,u0),cmul(B02,u2)); v01=cmul(B11,v01); v02=cadd(cmul(B20,u0),cmul(B22,u2)); }
  { float2 u0=v10,u2=v12; v10=cadd(cmul(B00,u0),cmul(B02,u2)); v11=cmul(B11,v11); v12=cadd(cmul(B20,u0),cmul(B22,u2)); }
  { float2 u0=v20,u2=v22; v20=cadd(cmul(B00,u0),cmul(B02,u2)); v21=cmul(B11,v21); v22=cadd(cmul(B20,u0),cmul(B22,u2)); }
  { float2 u0=v00,u2=v20; v00=cadd(cmul(A00,u0),cmul(A02,u2)); v10=cmul(A11,v10); v20=cadd(cmul(A20,u0),cmul(A22,u2)); }
  { float2 u0=v01,u2=v21; v01=cadd(cmul(A00,u0),cmul(A02,u2)); v11=cmul(A11,v11); v21=cadd(cmul(A20,u0),cmul(A22,u2)); }
  { float2 u0=v02,u2=v22; v02=cadd(cmul(A00,u0),cmul(A02,u2)); v12=cmul(A11,v12); v22=cadd(cmul(A20,u0),cmul(A22,u2)); }
  const float c=cs.x, s=cs.y;
  const float c2=c*c-s*s, s2=2.f*c*s, cc=c*c, ss=s*s, rcs=SQRT2f*c*s;
  BS2C(v01,v02,v10,v11,v12,v20,v21, c,s,c2,s2,cc,ss,rcs);
  p2[b]=v00;   p2[b+1]=v01; p2[b+2]=v02;
  p2[b+4]=v10; p2[b+5]=v11; p2[b+6]=v12;
  p2[b+8]=v20; p2[b+9]=v21; p2[b+10]=v22;
}

__device__ __forceinline__ void dpbs_n4(float2* __restrict__ p2, int b,
                                        const float2* __restrict__ G, float2 cs) {
  float2 v00=p2[b],   v01=p2[b+1], v02=p2[b+2];
  float2 v10=p2[b+4], v11=p2[b+5], v12=p2[b+6];
  float2 v20=p2[b+8], v21=p2[b+9], v22=p2[b+10];
  { float2 u0=v00,u1=v01,u2=v02;
    v00=cadd(cadd(cmul(G[9],u0),cmul(G[10],u1)),cmul(G[11],u2));
    v01=cadd(cadd(cmul(G[12],u0),cmul(G[13],u1)),cmul(G[14],u2));
    v02=cadd(cadd(cmul(G[15],u0),cmul(G[16],u1)),cmul(G[17],u2)); }
  { float2 u0=v10,u1=v11,u2=v12;
    v10=cadd(cadd(cmul(G[9],u0),cmul(G[10],u1)),cmul(G[11],u2));
    v11=cadd(cadd(cmul(G[12],u0),cmul(G[13],u1)),cmul(G[14],u2));
    v12=cadd(cadd(cmul(G[15],u0),cmul(G[16],u1)),cmul(G[17],u2)); }
  { float2 u0=v20,u1=v21,u2=v22;
    v20=cadd(cadd(cmul(G[9],u0),cmul(G[10],u1)),cmul(G[11],u2));
    v21=cadd(cadd(cmul(G[12],u0),cmul(G[13],u1)),cmul(G[14],u2));
    v22=cadd(cadd(cmul(G[15],u0),cmul(G[16],u1)),cmul(G[17],u2)); }
  { float2 u0=v00,u1=v10,u2=v20;
    v00=cadd(cadd(cmul(G[0],u0),cmul(G[1],u1)),cmul(G[2],u2));
    v10=cadd(cadd(cmul(G[3],u0),cmul(G[4],u1)),cmul(G[5],u2));
    v20=cadd(cadd(cmul(G[6],u0),cmul(G[7],u1)),cmul(G[8],u2)); }
  { float2 u0=v01,u1=v11,u2=v21;
    v01=cadd(cadd(cmul(G[0],u0),cmul(G[1],u1)),cmul(G[2],u2));
    v11=cadd(cadd(cmul(G[3],u0),cmul(G[4],u1)),cmul(G[5],u2));
    v21=cadd(cadd(cmul(G[6],u0),cmul(G[7],u1)),cmul(G[8],u2)); }
  { float2 u0=v02,u1=v12,u2=v22;
    v02=cadd(cadd(cmul(G[0],u0),cmul(G[1],u1)),cmul(G[2],u2));
    v12=cadd(cadd(cmul(G[3],u0),cmul(G[4],u1)),cmul(G[5],u2));
    v22=cadd(cadd(cmul(G[6],u0),cmul(G[7],u1)),cmul(G[8],u2)); }
  const float c=cs.x, s=cs.y;
  const float c2=c*c-s*s, s2=2.f*c*s, cc=c*c, ss=s*s, rcs=SQRT2f*c*s;
  BS2C(v01,v02,v10,v11,v12,v20,v21, c,s,c2,s2,cc,ss,rcs);
  p2[b]=v00;   p2[b+1]=v01; p2[b+2]=v02;
  p2[b+4]=v10; p2[b+5]=v11; p2[b+6]=v12;
  p2[b+8]=v20; p2[b+9]=v21; p2[b+10]=v22;
}

#define BASE4(g, s0,s1,s2,s3) ({ int _d=(g); int _b=(_d%3)*(s0); _d/=3; \
  _b += (_d%3)*(s1); _d/=3; _b += (_d%3)*(s2); _d/=3; _b += (_d%3)*(s3); _b; })
#define BASE5(g, s0,s1,s2,s3,s4) ({ int _d=(g); int _b=(_d%3)*(s0); _d/=3; \
  _b += (_d%3)*(s1); _d/=3; _b += (_d%3)*(s2); _d/=3; _b += (_d%3)*(s3); _d/=3; \
  _b += (_d%3)*(s4); _b; })

// DPK(L,mode)[i][j] = Kerr_i * U_disp[i][j] * phase^j (th2-layer phases)
__device__ __forceinline__ float2 dpk_entry(const float* __restrict__ dr,
                                            const float* __restrict__ th2,
                                            const float* __restrict__ kp,
                                            int L, int mode, int i, int j) {
  float sn, cn; sincosf(SQRT3f*dr[L*6+mode], &sn, &cn);
  float sw = sn*(1.f/SQRT3f), cw = (1.f-cn)*(1.f/3.f);
  float U;
  if      (i==0) U = (j==0) ? (1.f-cw)     : (j==1) ? (-sw)         : (SQRT2f*cw);
  else if (i==1) U = (j==0) ? (sw)         : (j==1) ? (1.f-3.f*cw)  : (-SQRT2f*sw);
  else           U = (j==0) ? (SQRT2f*cw)  : (j==1) ? (SQRT2f*sw)   : (1.f-2.f*cw);
  float2 ph = make_float2(1.f, 0.f);
  if (mode < 5) { float ps, pc; sincosf(th2[L*35+29+mode], &ps, &pc);
                  ph = make_float2(pc, ps); }
  float2 phj = (j==0) ? make_float2(1.f,0.f) : (j==1) ? ph : cmul(ph, ph);
  float ks, kc; sincosf(0.001f*kp[L*6+mode], &ks, &kc);
  float2 k1 = make_float2(kc, ks);
  float2 ki = (i==0) ? make_float2(1.f,0.f)
            : (i==1) ? k1 : cmul(cmul(k1,k1), cmul(k1,k1));
  float2 t = cmul(phj, ki);
  return make_float2(U*t.x, U*t.y);
}

// gtab (float2):
// [0,180)   BS (c,s): idx = (L*2+pass)*15 + pos (application order)
// [180,360) SQG: 180 + L*30 + c*10 : A(5) mode 2c, B(5) mode 2c+1 (th1 phases)
// [360,630) DPG: 360 + Ls*54 + c*18 : A(9) mode 2c, B(9) mode 2c+1 (layers 0..4)
// [630,684) Meas M_m = DPK(5,m)† X3 DPK(5,m): 630 + m*9 + i*3+j
// [684,690) init disp (sw,cw) per mode
// Padded psi layout (float2 units): strides n0:324 n1:108 n2:36 n3:12 n4:4 n5:1
__global__ __launch_bounds__(128)
void cvnn_kernel(const float* __restrict__ x,
                 const float* __restrict__ th1,
                 const float* __restrict__ th2,
                 const float* __restrict__ sr,
                 const float* __restrict__ dr,
                 const float* __restrict__ kp,
                 float* __restrict__ out) {
  __shared__ float4 psi4[486];          // 972 float2 slots, 16B-aligned
  __shared__ float2 gtab[690];
  __shared__ float red[12];
  float2* psi2 = (float2*)psi4;
  float4* P4 = psi4;

  const int tid = threadIdx.x;
  const int bidx = blockIdx.x;

  // ---- build gate table ----
  for (int f = tid; f < 690; f += 128) {
    float sn, cn; float2 v;
    if (f < 180) {
      int Lp = f/15, pos = f%15;
      int L = Lp/2, pass = Lp%2;
      float th = (pass ? th2 : th1)[L*35 + pos];
      sincosf(th, &sn, &cn); v = make_float2(cn, sn);
    } else if (f < 360) {
      int i = f - 180; int Lc = i/10, e = i%10;
      int L = Lc/3, c3 = Lc%3;
      int mode = 2*c3 + (e >= 5); int ee = e%5;
      float Sq, Cq; sincosf(0.25f*SQRT2f*sr[L*6+mode], &Sq, &Cq);
      float2 ph = make_float2(1.f, 0.f);
      if (mode < 5) { float ps, pc; sincosf(th1[L*35+29+mode], &ps, &pc);
                      ph = make_float2(pc, ps); }
      float2 ph2 = cmul(ph, ph);
      if      (ee == 0) v = make_float2(Cq, 0.f);
      else if (ee == 1) v = make_float2(Sq*ph2.x, Sq*ph2.y);
      else if (ee == 2) v = ph;
      else if (ee == 3) v = make_float2(-Sq, 0.f);
      else              v = make_float2(Cq*ph2.x, Cq*ph2.y);
    } else if (f < 630) {
      int i = f - 360; int Ld = i/18, e = i%18;
      int Ls = Ld/3, c3 = Ld%3;
      int mode = 2*c3 + (e >= 9); int ee = e%9;
      v = dpk_entry(dr, th2, kp, Ls, mode, ee/3, ee%3);
    } else if (f < 684) {
      int i = f - 630; int m = i/9, e = i%9;
      int ii = e/3, jj = e%3;
      float2 D0i = dpk_entry(dr, th2, kp, 5, m, 0, ii);
      float2 D1i = dpk_entry(dr, th2, kp, 5, m, 1, ii);
      float2 D2i = dpk_entry(dr, th2, kp, 5, m, 2, ii);
      float2 D0j = dpk_entry(dr, th2, kp, 5, m, 0, jj);
      float2 D1j = dpk_entry(dr, th2, kp, 5, m, 1, jj);
      float2 D2j = dpk_entry(dr, th2, kp, 5, m, 2, jj);
      float2 c0 = make_float2(D0i.x, -D0i.y);
      float2 c1 = make_float2(D1i.x, -D1i.y);
      float2 c2 = make_float2(D2i.x, -D2i.y);
      float2 acc = cmul(c0, D1j);
      float2 tmp = make_float2(D0j.x + SQRT2f*D2j.x, D0j.y + SQRT2f*D2j.y);
      acc = cadd(acc, cmul(c1, tmp));
      acc = cadd(acc, cmul(c2, make_float2(SQRT2f*D1j.x, SQRT2f*D1j.y)));
      v = acc;
    } else {
      int mode = f - 684;
      sincosf(SQRT3f*x[bidx*6 + mode], &sn, &cn);
      v = make_float2(sn*(1.f/SQRT3f), (1.f-cn)*(1.f/3.f));
    }
    gtab[f] = v;
  }
  __syncthreads();

  // ---- init: product state of displaced |0>, padded layout ----
  for (int idx = tid; idx < 972; idx += 128) {
    int n5 = idx & 3;
    float pr = 0.f;
    if (n5 != 3) {
      float2 d5 = gtab[684 + 5];
      pr = (n5==0) ? (1.f-d5.y) : (n5==1) ? d5.x : SQRT2f*d5.y;
      int d = idx >> 2;
#pragma unroll
      for (int mm = 4; mm >= 0; --mm) {
        int n = d % 3; d /= 3;
        float2 dc = gtab[684 + mm];
        pr *= (n==0) ? (1.f-dc.y) : (n==1) ? dc.x : SQRT2f*dc.y;
      }
    }
    psi2[idx] = make_float2(pr, 0.f);
  }

  // ---- per-thread bases ----
  // wide sweeps (k<=3): 54 threads = 27 combos x 2 n5-pairs; float4 units
  const int p  = tid & 1;
  const int cw = (tid < 54) ? (tid >> 1) : 0;
  const int wx = cw/9, wy = (cw/3)%3, wz = cw%3;
  const int bw0 = wx*18  + wy*6  + wz*2  + p;   // k0: free (n2,n3,n4)
  const int bw1 = wx*162 + wy*6  + wz*2  + p;   // k1: free (n0,n3,n4)
  const int bw2 = wx*162 + wy*54 + wz*2  + p;   // k2: free (n0,n1,n4)
  const int bw3 = wx*162 + wy*54 + wz*18 + p;   // k3: free (n0,n1,n2)
  // k4 narrow: 81 threads over (n0..n3); float2 units
  const int g4 = (tid < 81) ? tid : 0;
  const int b4n = BASE4(g4, 12, 36, 108, 324);
  __syncthreads();

  float2 csN = gtab[0];   // prefetch first sweep's (c,s)
  __syncthreads();

#define BSW0(NEXT) { if (tid < 54) bs_w<162,54>(P4, bw0, csN); \
    csN = gtab[NEXT]; __syncthreads(); }
#define BSW1(NEXT) { if (tid < 54) bs_w<54,18>(P4, bw1, csN); \
    csN = gtab[NEXT]; __syncthreads(); }
#define BSW2(NEXT) { if (tid < 54) bs_w<18,6>(P4, bw2, csN); \
    csN = gtab[NEXT]; __syncthreads(); }
#define BSW3(NEXT) { if (tid < 54) bs_w<6,2>(P4, bw3, csN); \
    csN = gtab[NEXT]; __syncthreads(); }
#define BSN4(NEXT) { if (tid < 81) bs_n4(psi2, b4n, csN); \
    csN = gtab[NEXT]; __syncthreads(); }
#define SQW0(GS,NEXT) { if (tid < 54) sqbs_w<162,54>(P4, bw0, &gtab[GS], csN); \
    csN = gtab[NEXT]; __syncthreads(); }
#define SQW2(GS,NEXT) { if (tid < 54) sqbs_w<18,6>(P4, bw2, &gtab[GS], csN); \
    csN = gtab[NEXT]; __syncthreads(); }
#define SQN4(GS,NEXT) { if (tid < 81) sqbs_n4(psi2, b4n, &gtab[GS], csN); \
    csN = gtab[NEXT]; __syncthreads(); }
#define DPW0(GD,NEXT) { if (tid < 54) dpbs_w<162,54>(P4, bw0, &gtab[GD], csN); \
    csN = gtab[NEXT]; __syncthreads(); }
#define DPW2(GD,NEXT) { if (tid < 54) dpbs_w<18,6>(P4, bw2, &gtab[GD], csN); \
    csN = gtab[NEXT]; __syncthreads(); }
#define DPN4(GD,NEXT) { if (tid < 81) dpbs_n4(psi2, b4n, &gtab[GD], csN); \
    csN = gtab[NEXT]; __syncthreads(); }

#pragma unroll
  for (int L = 0; L < 6; ++L) {
    const int i1 = (L*2)*15, i2 = (L*2+1)*15;
    // pass 1: first course folds previous layer's DPK (L>=1)
    if (L == 0) {
      BSW0(i1+1); BSW2(i1+2); BSN4(i1+3);
    } else {
      const int gd = 360 + (L-1)*54;
      DPW0(gd+0, i1+1); DPW2(gd+18, i1+2); DPN4(gd+36, i1+3);
    }
    BSW1(i1+4);  BSW3(i1+5);
    BSW0(i1+6);  BSW2(i1+7);  BSN4(i1+8);
    BSW1(i1+9);  BSW3(i1+10);
    BSW0(i1+11); BSW2(i1+12); BSN4(i1+13);
    BSW1(i1+14); BSW3(i2+0);
    // pass 2: first course folds this layer's SQ (+th1 phases)
    {
      const int gs = 180 + L*30;
      SQW0(gs+0, i2+1); SQW2(gs+10, i2+2); SQN4(gs+20, i2+3);
    }
    BSW1(i2+4);  BSW3(i2+5);
    BSW0(i2+6);  BSW2(i2+7);  BSN4(i2+8);
    BSW1(i2+9);  BSW3(i2+10);
    BSW0(i2+11); BSW2(i2+12); BSN4(i2+13);
    BSW1(i2+14); BSW3((L < 5) ? (L+1)*30 : 0);
  }

  // ---- <X_m> via folded Hermitian M_m = DPK(5,m)† X DPK(5,m) ----
  float xs[6] = {0.f,0.f,0.f,0.f,0.f,0.f};
  for (int it = 0; it < 2; ++it) {
    int t = tid + (it << 7);
    if (t < 243) {
#define XACC(m, SS, BB) { int b_ = (BB); \
      const float2* M_ = &gtab[630 + (m)*9]; \
      float d0 = M_[0].x, d1 = M_[4].x, d2 = M_[8].x; \
      float2 M01 = M_[1], M02 = M_[2], M12 = M_[5]; \
      float2 a_ = psi2[b_]; float2 e_ = psi2[b_+(SS)]; float2 f_ = psi2[b_+2*(SS)]; \
      xs[m] += d0*(a_.x*a_.x + a_.y*a_.y) + d1*(e_.x*e_.x + e_.y*e_.y) \
             + d2*(f_.x*f_.x + f_.y*f_.y) \
        + 2.f*(M01.x*(a_.x*e_.x + a_.y*e_.y) - M01.y*(a_.x*e_.y - a_.y*e_.x)) \
        + 2.f*(M02.x*(a_.x*f_.x + a_.y*f_.y) - M02.y*(a_.x*f_.y - a_.y*f_.x)) \
        + 2.f*(M12.x*(e_.x*f_.x + e_.y*f_.y) - M12.y*(e_.x*f_.y - e_.y*f_.x)); }
      XACC(0, 324, BASE5(t, 1, 4, 12, 36, 108));
      XACC(1, 108, BASE5(t, 1, 4, 12, 36, 324));
      XACC(2, 36,  BASE5(t, 1, 4, 12, 108, 324));
      XACC(3, 12,  BASE5(t, 1, 4, 36, 108, 324));
      XACC(4, 4,   BASE5(t, 1, 12, 36, 108, 324));
      XACC(5, 1,   BASE5(t, 4, 12, 36, 108, 324));
    }
  }
  const int wid = tid >> 6;
#pragma unroll
  for (int m = 0; m < 6; ++m) {
    float v = xs[m];
    for (int off = 32; off > 0; off >>= 1) v += __shfl_down(v, off);
    if ((tid & 63) == 0) red[wid*6 + m] = v;
  }
  __syncthreads();
  if (tid < 6) out[bidx*6 + tid] = red[tid] + red[6 + tid];
}

extern "C" void kernel_launch(void* const* d_in, const int* in_sizes, int n_in,
                              void* d_out, int out_size, void* d_ws, size_t ws_size,
                              hipStream_t stream) {
  const float* x  = (const float*)d_in[0];
  const float* t1 = (const float*)d_in[1];
  const float* t2 = (const float*)d_in[2];
  const float* sr = (const float*)d_in[3];
  const float* dr = (const float*)d_in[4];
  const float* kp = (const float*)d_in[5];
  const int B = in_sizes[0] / 6;
  cvnn_kernel<<<B, 128, 0, stream>>>(x, t1, t2, sr, dr, kp, (float*)d_out);
}